// Round 2
// baseline (163.025 us; speedup 1.0000x reference)
//
#include <hip/hip_runtime.h>

#define DIM 4096  // 2^12 amplitudes

// ---------------------------------------------------------------------------
// Kernel 1: simulate 8 columns of the fixed post-encoding unitary U.
// Block b computes u_k = U e_{k<<9}, state held in LDS as float2 (re,im).
// Qubit w corresponds to bit (11-w) of the amplitude index (q0 = MSB).
// ---------------------------------------------------------------------------
__global__ __launch_bounds__(1024) void sim_columns(const float* __restrict__ w,
                                                    float2* __restrict__ u) {
  __shared__ float2 st[DIM];
  const int tid = threadIdx.x;
  const int nt = 1024;
  const int k = blockIdx.x;  // 0..7

  for (int i = tid; i < DIM; i += nt) st[i] = make_float2(0.f, 0.f);
  __syncthreads();
  if (tid == 0) st[k << 9] = make_float2(1.f, 0.f);
  __syncthreads();

  // fused RY(thy) followed by optional RZ(thz) on qubit q
  auto rot = [&](int q, float thy, float thz, bool has_rz) {
    const int bp = 11 - q;
    const float c = cosf(0.5f * thy), s = sinf(0.5f * thy);
    float cz = 1.f, sz = 0.f;
    if (has_rz) { cz = cosf(0.5f * thz); sz = sinf(0.5f * thz); }
    for (int p = tid; p < DIM / 2; p += nt) {
      const int lo = p & ((1 << bp) - 1);
      const int i0 = ((p >> bp) << (bp + 1)) | lo;
      const int i1 = i0 | (1 << bp);
      const float2 a0 = st[i0], a1 = st[i1];
      // RY: r0 = c*a0 - s*a1 ; r1 = s*a0 + c*a1  (c,s real)
      const float r0x = c * a0.x - s * a1.x, r0y = c * a0.y - s * a1.y;
      const float r1x = s * a0.x + c * a1.x, r1y = s * a0.y + c * a1.y;
      // RZ: a0 *= (cz - i sz) ; a1 *= (cz + i sz)
      st[i0] = make_float2(cz * r0x + sz * r0y, cz * r0y - sz * r0x);
      st[i1] = make_float2(cz * r1x - sz * r1y, cz * r1y + sz * r1x);
    }
    __syncthreads();
  };

  // CNOT(control cq, target tq): for control-bit==1, swap target bit
  auto cnot = [&](int cq, int tq) {
    const int bc = 11 - cq, bt = 11 - tq;
    for (int i = tid; i < DIM; i += nt) {
      if (((i >> bc) & 1) && !((i >> bt) & 1)) {
        const int j = i | (1 << bt);
        const float2 t0 = st[i];
        st[i] = st[j];
        st[j] = t0;
      }
    }
    __syncthreads();
  };

  // rot layer W0/W1
  for (int q = 0; q < 12; q++) rot(q, w[0 * 12 + q], w[1 * 12 + q], true);
  // entangling: c in 0..2, t in 3..7 then t in 8..11
  for (int c = 0; c < 3; c++)
    for (int t = 3; t < 8; t++) cnot(c, t);
  for (int c = 0; c < 3; c++)
    for (int t = 8; t < 12; t++) cnot(c, t);
  // rot layer W2/W3
  for (int q = 0; q < 12; q++) rot(q, w[2 * 12 + q], w[3 * 12 + q], true);
  // pk ring (3,4,5,6,7) and pd ring (8,9,10,11)
  {
    const int pk[5] = {3, 4, 5, 6, 7};
    for (int i = 0; i < 5; i++) cnot(pk[i], pk[(i + 1) % 5]);
    const int pd[4] = {8, 9, 10, 11};
    for (int i = 0; i < 4; i++) cnot(pd[i], pd[(i + 1) % 4]);
  }
  // rot layer W4/W5
  for (int q = 0; q < 12; q++) rot(q, w[4 * 12 + q], w[5 * 12 + q], true);
  // cross couplings
  {
    const int cc[5] = {3, 4, 5, 6, 7}, tt[5] = {8, 9, 10, 11, 8};
    for (int i = 0; i < 5; i++) cnot(cc[i], tt[i]);
  }
  // rot layer W6/W7
  for (int q = 0; q < 12; q++) rot(q, w[6 * 12 + q], w[7 * 12 + q], true);
  // final RY-only layer W8
  for (int q = 0; q < 12; q++) rot(q, w[8 * 12 + q], 0.f, false);

  for (int i = tid; i < DIM; i += nt) u[k * DIM + i] = st[i];
}

// ---------------------------------------------------------------------------
// Kernel 2: A_q[k][k'] = sum_i z_q(i) * Re(u_k[i] * conj(u_k'[i]))
// block q in 0..8 (observable qubit 3+q -> bit (8-q)); writes full 8x8.
// ---------------------------------------------------------------------------
__global__ __launch_bounds__(256) void make_A(const float2* __restrict__ u,
                                              float* __restrict__ A) {
  const int q = blockIdx.x;  // 0..8
  const int bp = 8 - q;
  const int tid = threadIdx.x;

  float acc[36];
#pragma unroll
  for (int j = 0; j < 36; j++) acc[j] = 0.f;

  for (int i = tid; i < DIM; i += 256) {
    float re[8], im[8];
#pragma unroll
    for (int k = 0; k < 8; k++) {
      const float2 v = u[k * DIM + i];
      re[k] = v.x;
      im[k] = v.y;
    }
    const float z = ((i >> bp) & 1) ? -1.f : 1.f;
    int j = 0;
#pragma unroll
    for (int k = 0; k < 8; k++)
#pragma unroll
      for (int kp = 0; kp <= k; kp++, j++)
        acc[j] += z * (re[k] * re[kp] + im[k] * im[kp]);
  }

  __shared__ float red[4][36];
  const int lane = tid & 63, wave = tid >> 6;
#pragma unroll
  for (int j = 0; j < 36; j++) {
    float v = acc[j];
    for (int off = 32; off > 0; off >>= 1) v += __shfl_down(v, off, 64);
    if (lane == 0) red[wave][j] = v;
  }
  __syncthreads();
  if (tid < 36) {
    const float v = red[0][tid] + red[1][tid] + red[2][tid] + red[3][tid];
    int k = 0;
    while ((k + 1) * (k + 2) / 2 <= tid) k++;
    const int kp = tid - k * (k + 1) / 2;
    A[q * 64 + k * 8 + kp] = v;
    A[q * 64 + kp * 8 + k] = v;
  }
}

// ---------------------------------------------------------------------------
// Kernel 3: per batch element: alpha from encoding angles, ev_q = a^T A_q a,
// map to bounds, write pk (B,5) then pd (B,4) concatenated.
// ---------------------------------------------------------------------------
__global__ __launch_bounds__(256) void eval_batch(
    const float* __restrict__ cov, const float* __restrict__ dose,
    const float* __restrict__ A, const float* __restrict__ pkb,
    const float* __restrict__ pdb, float* __restrict__ out, int B) {
  __shared__ float As[9 * 64];
  for (int j = threadIdx.x; j < 9 * 64; j += blockDim.x) As[j] = A[j];
  __syncthreads();

  const int b = blockIdx.x * blockDim.x + threadIdx.x;
  if (b >= B) return;

  const float th0 = cov[b * 2 + 0], th1 = cov[b * 2 + 1], th2 = dose[b];
  const float c0 = cosf(0.5f * th0), s0 = sinf(0.5f * th0);
  const float c1 = cosf(0.5f * th1), s1 = sinf(0.5f * th1);
  const float c2 = cosf(0.5f * th2), s2 = sinf(0.5f * th2);

  float alpha[8];
#pragma unroll
  for (int k = 0; k < 8; k++) {
    const float f0 = (k & 4) ? s0 : c0;
    const float f1 = (k & 2) ? s1 : c1;
    const float f2 = (k & 1) ? s2 : c2;
    alpha[k] = f0 * f1 * f2;
  }

#pragma unroll
  for (int q = 0; q < 9; q++) {
    float ev = 0.f;
#pragma unroll
    for (int k = 0; k < 8; k++) {
      float t = 0.f;
#pragma unroll
      for (int kp = 0; kp < 8; kp++) t += As[q * 64 + k * 8 + kp] * alpha[kp];
      ev += alpha[k] * t;
    }
    const float norm = (ev + 1.f) * 0.5f;
    if (q < 5) {
      const float lo = pkb[q * 2], hi = pkb[q * 2 + 1];
      out[b * 5 + q] = lo + norm * (hi - lo);
    } else {
      const int j = q - 5;
      const float lo = pdb[j * 2], hi = pdb[j * 2 + 1];
      out[B * 5 + b * 4 + j] = lo + norm * (hi - lo);
    }
  }
}

// ---------------------------------------------------------------------------
extern "C" void kernel_launch(void* const* d_in, const int* in_sizes, int n_in,
                              void* d_out, int out_size, void* d_ws,
                              size_t ws_size, hipStream_t stream) {
  // inputs: 0 subject_ids (unused), 1 covariates (B,2) f32, 2 dose (B,) f32,
  //         3 weights (108,) f32, 4 pk_bounds (5,2) f32, 5 pd_bounds (4,2) f32
  const float* cov = (const float*)d_in[1];
  const float* dose = (const float*)d_in[2];
  const float* wts = (const float*)d_in[3];
  const float* pkb = (const float*)d_in[4];
  const float* pdb = (const float*)d_in[5];
  float* out = (float*)d_out;
  const int B = in_sizes[2];

  float2* u = (float2*)d_ws;                                    // 8*4096 float2
  float* A = (float*)((char*)d_ws + 8 * DIM * sizeof(float2));  // 9*64 floats

  hipLaunchKernelGGL(sim_columns, dim3(8), dim3(1024), 0, stream, wts, u);
  hipLaunchKernelGGL(make_A, dim3(9), dim3(256), 0, stream, u, A);
  hipLaunchKernelGGL(eval_batch, dim3((B + 255) / 256), dim3(256), 0, stream,
                     cov, dose, A, pkb, pdb, out, B);
}

// Round 3
// 103.101 us; speedup vs baseline: 1.5812x; 1.5812x over previous
//
#include <hip/hip_runtime.h>

// ===========================================================================
// Algebraic reduction:
//  - Entangling block CNOT(c in 0..2 -> every t in 3..11) == "flip all 9
//    target qubits iff parity(q0,q1,q2)==1".
//  - Qubits 0..2 are never entangled afterwards; observables act on 3..11
//    only, so all later single-qubit gates on 0..2 cancel in the reduced
//    density matrix.
//  => rho_{3..11} = (1-Podd)|psi0><psi0| + Podd|psi1><psi1| with
//     psi0 = V|chi>, psi1 = V X^x9 |chi>, V = remaining circuit on 9 qubits,
//     chi = prod_q RZ(W1q)RY(W0q)|0>.
//     Podd(b) = 0.5*(1 - cos(t0+W00)cos(t1+W01)cos(t2+W02)).
//  => ev_q(b) = e0_q + (e1_q - e0_q)*Podd(b);  e0/e1 batch-independent.
//
// The 512-dim sims run entirely in one wave's registers: 8 complex amps per
// lane. Amplitude index i (9 bits): bits 0..2 = register index (qubits
// 9,10,11), bits 3..8 = lane index (qubits 3..8). Lane-qubit gates use
// __shfl_xor; register-qubit gates are pure VALU; no LDS, no barriers.
// ===========================================================================

// --- rotation RY(thy) then RZ(thz) on bit-position BP (0..8) ---------------
template <int BP>
__device__ inline void rot_gate(float (&re)[8], float (&im)[8], float c,
                                float s, float cz, float sz) {
  if constexpr (BP < 3) {  // register qubit
    constexpr int m = 1 << BP;
#pragma unroll
    for (int r = 0; r < 8; r++) {
      if (!(r & m)) {
        const int r1 = r | m;
        const float a0r = re[r], a0i = im[r], a1r = re[r1], a1i = im[r1];
        const float n0r = c * a0r - s * a1r, n0i = c * a0i - s * a1i;
        const float n1r = s * a0r + c * a1r, n1i = s * a0i + c * a1i;
        re[r] = cz * n0r + sz * n0i;   // * (cz - i sz)
        im[r] = cz * n0i - sz * n0r;
        re[r1] = cz * n1r - sz * n1i;  // * (cz + i sz)
        im[r1] = cz * n1i + sz * n1r;
      }
    }
  } else {  // lane qubit
    constexpr int lm = 1 << (BP - 3);
    const int bit = (threadIdx.x >> (BP - 3)) & 1;
    const float sy = bit ? s : -s;    // new = c*a + sy*partner
    const float so = bit ? -sz : sz;  // re'=cz*re+so*im ; im'=cz*im-so*re
#pragma unroll
    for (int r = 0; r < 8; r++) {
      const float pr = __shfl_xor(re[r], lm, 64);
      const float pi = __shfl_xor(im[r], lm, 64);
      const float nr = c * re[r] + sy * pr;
      const float ni = c * im[r] + sy * pi;
      re[r] = cz * nr + so * ni;
      im[r] = cz * ni - so * nr;
    }
  }
}

// --- CNOTs by operand location ---------------------------------------------
template <int CB, int TB>  // control reg-bit, target reg-bit
__device__ inline void cnot_rr(float (&re)[8], float (&im)[8]) {
#pragma unroll
  for (int r = 0; r < 8; r++)
    if ((r & (1 << CB)) && !(r & (1 << TB))) {
      const int r1 = r | (1 << TB);
      float t = re[r]; re[r] = re[r1]; re[r1] = t;
      t = im[r]; im[r] = im[r1]; im[r1] = t;
    }
}
template <int CB, int TL>  // control reg-bit, target lane-bit
__device__ inline void cnot_rl(float (&re)[8], float (&im)[8]) {
#pragma unroll
  for (int r = 0; r < 8; r++)
    if (r & (1 << CB)) {
      re[r] = __shfl_xor(re[r], 1 << TL, 64);
      im[r] = __shfl_xor(im[r], 1 << TL, 64);
    }
}
template <int CL, int TB>  // control lane-bit, target reg-bit
__device__ inline void cnot_lr(float (&re)[8], float (&im)[8]) {
  const bool c = (threadIdx.x >> CL) & 1;
#pragma unroll
  for (int r = 0; r < 8; r++)
    if (!(r & (1 << TB))) {
      const int r1 = r | (1 << TB);
      const float t0r = re[r], t0i = im[r];
      re[r] = c ? re[r1] : re[r];
      im[r] = c ? im[r1] : im[r];
      re[r1] = c ? t0r : re[r1];
      im[r1] = c ? t0i : im[r1];
    }
}
template <int CL, int TL>  // control lane-bit, target lane-bit
__device__ inline void cnot_ll(float (&re)[8], float (&im)[8]) {
  const bool c = (threadIdx.x >> CL) & 1;
#pragma unroll
  for (int r = 0; r < 8; r++) {
    const float pr = __shfl_xor(re[r], 1 << TL, 64);
    const float pi = __shfl_xor(im[r], 1 << TL, 64);
    re[r] = c ? pr : re[r];
    im[r] = c ? pi : im[r];
  }
}

// --- one rot layer over qubits 3..11 (qubit q -> BP = 11-q) ----------------
__device__ inline void rot_layer(float (&re)[8], float (&im)[8],
                                 const float* __restrict__ w, int ly, int lz,
                                 bool has_rz) {
#define ROTQ(Q, BP)                                              \
  {                                                              \
    const float th = 0.5f * w[ly * 12 + Q];                      \
    const float c = cosf(th), s = sinf(th);                      \
    float cz = 1.f, sz = 0.f;                                    \
    if (has_rz) {                                                \
      const float tz = 0.5f * w[lz * 12 + Q];                    \
      cz = cosf(tz);                                             \
      sz = sinf(tz);                                             \
    }                                                            \
    rot_gate<BP>(re, im, c, s, cz, sz);                          \
  }
  ROTQ(3, 8) ROTQ(4, 7) ROTQ(5, 6) ROTQ(6, 5) ROTQ(7, 4)
  ROTQ(8, 3) ROTQ(9, 2) ROTQ(10, 1) ROTQ(11, 0)
#undef ROTQ
}

// --- flip all 9 bits: i -> i ^ 0x1FF ---------------------------------------
__device__ inline void x_all(float (&re)[8], float (&im)[8]) {
  float tr[8], ti[8];
#pragma unroll
  for (int r = 0; r < 8; r++) {
    tr[r] = __shfl_xor(re[r ^ 7], 63, 64);
    ti[r] = __shfl_xor(im[r ^ 7], 63, 64);
  }
#pragma unroll
  for (int r = 0; r < 8; r++) { re[r] = tr[r]; im[r] = ti[r]; }
}

// --- full 9-qubit sim for initial-flip s; ev[9] valid in all lanes ---------
__device__ inline void simulate(const float* __restrict__ w, int s,
                                float (&ev)[9]) {
  float re[8], im[8];
#pragma unroll
  for (int r = 0; r < 8; r++) { re[r] = 0.f; im[r] = 0.f; }
  if ((threadIdx.x & 63) == 0) re[0] = 1.f;

  rot_layer(re, im, w, 0, 1, true);
  if (s) x_all(re, im);
  rot_layer(re, im, w, 2, 3, true);
  // pk ring: (3,4)(4,5)(5,6)(6,7)(7,3)   [q: 3->L5 4->L4 5->L3 6->L2 7->L1 8->L0 9->R2 10->R1 11->R0]
  cnot_ll<5, 4>(re, im);
  cnot_ll<4, 3>(re, im);
  cnot_ll<3, 2>(re, im);
  cnot_ll<2, 1>(re, im);
  cnot_ll<1, 5>(re, im);
  // pd ring: (8,9)(9,10)(10,11)(11,8)
  cnot_lr<0, 2>(re, im);
  cnot_rr<2, 1>(re, im);
  cnot_rr<1, 0>(re, im);
  cnot_rl<0, 0>(re, im);
  rot_layer(re, im, w, 4, 5, true);
  // cross: (3,8)(4,9)(5,10)(6,11)(7,8)
  cnot_ll<5, 0>(re, im);
  cnot_lr<4, 2>(re, im);
  cnot_lr<3, 1>(re, im);
  cnot_lr<2, 0>(re, im);
  cnot_ll<1, 0>(re, im);
  rot_layer(re, im, w, 6, 7, true);
  rot_layer(re, im, w, 8, 8, false);

  // expectations: obs ob=0..8 measures qubit 3+ob -> bit 8-ob
  float p[8], tot = 0.f;
#pragma unroll
  for (int r = 0; r < 8; r++) {
    p[r] = re[r] * re[r] + im[r] * im[r];
    tot += p[r];
  }
#pragma unroll
  for (int ob = 0; ob < 6; ob++) {  // lane bits 5..0
    const int lb = 5 - ob;
    ev[ob] = ((threadIdx.x >> lb) & 1) ? -tot : tot;
  }
#pragma unroll
  for (int ob = 6; ob < 9; ob++) {  // reg bits 2..0
    const int rb = 8 - ob;
    float v = 0.f;
#pragma unroll
    for (int r = 0; r < 8; r++) v += ((r >> rb) & 1) ? -p[r] : p[r];
    ev[ob] = v;
  }
#pragma unroll
  for (int ob = 0; ob < 9; ob++)
    for (int off = 1; off < 64; off <<= 1)
      ev[ob] += __shfl_xor(ev[ob], off, 64);
}

// ===========================================================================
__global__ __launch_bounds__(256) void qnpe_fused(
    const float* __restrict__ cov, const float* __restrict__ dose,
    const float* __restrict__ w, const float* __restrict__ pkb,
    const float* __restrict__ pdb, float* __restrict__ out, int B) {
  __shared__ float eS[2][9];
  const int wave = threadIdx.x >> 6;
  if (wave < 2) {  // waves 0,1 redundantly simulate psi0 / psi1
    float ev[9];
    simulate(w, wave, ev);
    if ((threadIdx.x & 63) == 0)
#pragma unroll
      for (int ob = 0; ob < 9; ob++) eS[wave][ob] = ev[ob];
  }
  __syncthreads();

  const int b = blockIdx.x * blockDim.x + threadIdx.x;
  if (b >= B) return;

  const float g = cosf(cov[2 * b] + w[0]) * cosf(cov[2 * b + 1] + w[1]) *
                  cosf(dose[b] + w[2]);
  const float podd = 0.5f * (1.f - g);

#pragma unroll
  for (int q = 0; q < 9; q++) {
    const float e = eS[0][q] + (eS[1][q] - eS[0][q]) * podd;
    const float norm = 0.5f * (e + 1.f);
    if (q < 5) {
      out[b * 5 + q] = pkb[2 * q] + norm * (pkb[2 * q + 1] - pkb[2 * q]);
    } else {
      const int j = q - 5;
      out[B * 5 + b * 4 + j] = pdb[2 * j] + norm * (pdb[2 * j + 1] - pdb[2 * j]);
    }
  }
}

// ===========================================================================
extern "C" void kernel_launch(void* const* d_in, const int* in_sizes, int n_in,
                              void* d_out, int out_size, void* d_ws,
                              size_t ws_size, hipStream_t stream) {
  // inputs: 0 subject_ids (unused), 1 covariates (B,2) f32, 2 dose (B,) f32,
  //         3 weights (108,) f32, 4 pk_bounds (5,2) f32, 5 pd_bounds (4,2) f32
  const float* cov = (const float*)d_in[1];
  const float* dose = (const float*)d_in[2];
  const float* wts = (const float*)d_in[3];
  const float* pkb = (const float*)d_in[4];
  const float* pdb = (const float*)d_in[5];
  float* out = (float*)d_out;
  const int B = in_sizes[2];

  hipLaunchKernelGGL(qnpe_fused, dim3((B + 255) / 256), dim3(256), 0, stream,
                     cov, dose, wts, pkb, pdb, out, B);
}

// Round 4
// 73.771 us; speedup vs baseline: 2.2099x; 1.3976x over previous
//
#include <hip/hip_runtime.h>

// ===========================================================================
// Algebraic reduction (verified round 2/3, absmax 0.0156 vs threshold 3.84):
//  - Entangling block CNOT(c in 0..2 -> every t in 3..11) == "flip all 9
//    target qubits iff parity(q0,q1,q2)==1".
//  - Qubits 0..2 never entangled afterwards; observables act on 3..11 only,
//    so later single-qubit gates on 0..2 cancel in the reduced density matrix.
//  => rho_{3..11} = (1-Podd)|psi0><psi0| + Podd|psi1><psi1|,
//     psi0 = V|chi>, psi1 = V X^x9 |chi>;
//     Podd(b) = 0.5*(1 - cos(t0+W00)cos(t1+W01)cos(t2+W02)).
//  => ev_q(b) = e0_q + (e1_q - e0_q)*Podd(b);  e0/e1 batch-independent.
//
// 512-dim sims live in one wave's registers (8 complex amps/lane):
// amp index bits 0..2 = register (qubits 9,10,11), bits 3..8 = lane
// (qubits 3..8). Lane gates = __shfl_xor, register gates = VALU.
//
// Round-4 change: ALL trig is precomputed in parallel (108 threads, one
// __sincosf each -> LDS) instead of ~252 serial cosf/sinf calls inside the
// gate chain — that serial transcendental chain was the 47 us (round-3
// counters: VALUBusy 0.66%, no LDS conflicts, no HBM — pure latency chain).
// ===========================================================================

// --- rotation RY then RZ on bit-position BP (0..8) -------------------------
template <int BP>
__device__ inline void rot_gate(float (&re)[8], float (&im)[8], float c,
                                float s, float cz, float sz) {
  if constexpr (BP < 3) {  // register qubit
    constexpr int m = 1 << BP;
#pragma unroll
    for (int r = 0; r < 8; r++) {
      if (!(r & m)) {
        const int r1 = r | m;
        const float a0r = re[r], a0i = im[r], a1r = re[r1], a1i = im[r1];
        const float n0r = c * a0r - s * a1r, n0i = c * a0i - s * a1i;
        const float n1r = s * a0r + c * a1r, n1i = s * a0i + c * a1i;
        re[r] = cz * n0r + sz * n0i;   // * (cz - i sz)
        im[r] = cz * n0i - sz * n0r;
        re[r1] = cz * n1r - sz * n1i;  // * (cz + i sz)
        im[r1] = cz * n1i + sz * n1r;
      }
    }
  } else {  // lane qubit
    constexpr int lm = 1 << (BP - 3);
    const int bit = (threadIdx.x >> (BP - 3)) & 1;
    const float sy = bit ? s : -s;    // new = c*a + sy*partner
    const float so = bit ? -sz : sz;  // re'=cz*re+so*im ; im'=cz*im-so*re
#pragma unroll
    for (int r = 0; r < 8; r++) {
      const float pr = __shfl_xor(re[r], lm, 64);
      const float pi = __shfl_xor(im[r], lm, 64);
      const float nr = c * re[r] + sy * pr;
      const float ni = c * im[r] + sy * pi;
      re[r] = cz * nr + so * ni;
      im[r] = cz * ni - so * nr;
    }
  }
}

// --- CNOTs by operand location ---------------------------------------------
template <int CB, int TB>
__device__ inline void cnot_rr(float (&re)[8], float (&im)[8]) {
#pragma unroll
  for (int r = 0; r < 8; r++)
    if ((r & (1 << CB)) && !(r & (1 << TB))) {
      const int r1 = r | (1 << TB);
      float t = re[r]; re[r] = re[r1]; re[r1] = t;
      t = im[r]; im[r] = im[r1]; im[r1] = t;
    }
}
template <int CB, int TL>
__device__ inline void cnot_rl(float (&re)[8], float (&im)[8]) {
#pragma unroll
  for (int r = 0; r < 8; r++)
    if (r & (1 << CB)) {
      re[r] = __shfl_xor(re[r], 1 << TL, 64);
      im[r] = __shfl_xor(im[r], 1 << TL, 64);
    }
}
template <int CL, int TB>
__device__ inline void cnot_lr(float (&re)[8], float (&im)[8]) {
  const bool c = (threadIdx.x >> CL) & 1;
#pragma unroll
  for (int r = 0; r < 8; r++)
    if (!(r & (1 << TB))) {
      const int r1 = r | (1 << TB);
      const float t0r = re[r], t0i = im[r];
      re[r] = c ? re[r1] : re[r];
      im[r] = c ? im[r1] : im[r];
      re[r1] = c ? t0r : re[r1];
      im[r1] = c ? t0i : im[r1];
    }
}
template <int CL, int TL>
__device__ inline void cnot_ll(float (&re)[8], float (&im)[8]) {
  const bool c = (threadIdx.x >> CL) & 1;
#pragma unroll
  for (int r = 0; r < 8; r++) {
    const float pr = __shfl_xor(re[r], 1 << TL, 64);
    const float pi = __shfl_xor(im[r], 1 << TL, 64);
    re[r] = c ? pr : re[r];
    im[r] = c ? pi : im[r];
  }
}

// --- one rot layer over qubits 3..11 (qubit q -> BP = 11-q) ----------------
// cs[0][i] = cos(0.5*w[i]), cs[1][i] = sin(0.5*w[i]) — precomputed in LDS.
__device__ inline void rot_layer(float (&re)[8], float (&im)[8],
                                 const float (*cs)[108], int ly, int lz,
                                 bool has_rz) {
#define ROTQ(Q, BP)                                                  \
  {                                                                  \
    const float c = cs[0][ly * 12 + Q], s = cs[1][ly * 12 + Q];      \
    float cz = 1.f, sz = 0.f;                                        \
    if (has_rz) { cz = cs[0][lz * 12 + Q]; sz = cs[1][lz * 12 + Q]; }\
    rot_gate<BP>(re, im, c, s, cz, sz);                              \
  }
  ROTQ(3, 8) ROTQ(4, 7) ROTQ(5, 6) ROTQ(6, 5) ROTQ(7, 4)
  ROTQ(8, 3) ROTQ(9, 2) ROTQ(10, 1) ROTQ(11, 0)
#undef ROTQ
}

// --- flip all 9 bits: i -> i ^ 0x1FF ---------------------------------------
__device__ inline void x_all(float (&re)[8], float (&im)[8]) {
  float tr[8], ti[8];
#pragma unroll
  for (int r = 0; r < 8; r++) {
    tr[r] = __shfl_xor(re[r ^ 7], 63, 64);
    ti[r] = __shfl_xor(im[r ^ 7], 63, 64);
  }
#pragma unroll
  for (int r = 0; r < 8; r++) { re[r] = tr[r]; im[r] = ti[r]; }
}

// --- full 9-qubit sim for initial-flip s; ev[9] valid in all lanes ---------
__device__ inline void simulate(const float (*cs)[108], int s, float (&ev)[9]) {
  float re[8], im[8];
#pragma unroll
  for (int r = 0; r < 8; r++) { re[r] = 0.f; im[r] = 0.f; }
  if ((threadIdx.x & 63) == 0) re[0] = 1.f;

  rot_layer(re, im, cs, 0, 1, true);
  if (s) x_all(re, im);
  rot_layer(re, im, cs, 2, 3, true);
  // pk ring: (3,4)(4,5)(5,6)(6,7)(7,3)  [q: 3->L5 4->L4 5->L3 6->L2 7->L1
  //                                         8->L0 9->R2 10->R1 11->R0]
  cnot_ll<5, 4>(re, im);
  cnot_ll<4, 3>(re, im);
  cnot_ll<3, 2>(re, im);
  cnot_ll<2, 1>(re, im);
  cnot_ll<1, 5>(re, im);
  // pd ring: (8,9)(9,10)(10,11)(11,8)
  cnot_lr<0, 2>(re, im);
  cnot_rr<2, 1>(re, im);
  cnot_rr<1, 0>(re, im);
  cnot_rl<0, 0>(re, im);
  rot_layer(re, im, cs, 4, 5, true);
  // cross: (3,8)(4,9)(5,10)(6,11)(7,8)
  cnot_ll<5, 0>(re, im);
  cnot_lr<4, 2>(re, im);
  cnot_lr<3, 1>(re, im);
  cnot_lr<2, 0>(re, im);
  cnot_ll<1, 0>(re, im);
  rot_layer(re, im, cs, 6, 7, true);
  rot_layer(re, im, cs, 8, 8, false);

  // expectations: obs ob=0..8 measures qubit 3+ob -> bit 8-ob
  float p[8], tot = 0.f;
#pragma unroll
  for (int r = 0; r < 8; r++) {
    p[r] = re[r] * re[r] + im[r] * im[r];
    tot += p[r];
  }
#pragma unroll
  for (int ob = 0; ob < 6; ob++) {  // lane bits 5..0
    const int lb = 5 - ob;
    ev[ob] = ((threadIdx.x >> lb) & 1) ? -tot : tot;
  }
#pragma unroll
  for (int ob = 6; ob < 9; ob++) {  // reg bits 2..0
    const int rb = 8 - ob;
    float v = 0.f;
#pragma unroll
    for (int r = 0; r < 8; r++) v += ((r >> rb) & 1) ? -p[r] : p[r];
    ev[ob] = v;
  }
#pragma unroll
  for (int ob = 0; ob < 9; ob++)
    for (int off = 1; off < 64; off <<= 1)
      ev[ob] += __shfl_xor(ev[ob], off, 64);
}

// ===========================================================================
__global__ __launch_bounds__(256) void qnpe_fused(
    const float* __restrict__ cov, const float* __restrict__ dose,
    const float* __restrict__ w, const float* __restrict__ pkb,
    const float* __restrict__ pdb, float* __restrict__ out, int B) {
  __shared__ float csn[2][108];  // cos/sin of 0.5*w[i], computed in parallel
  __shared__ float eS[2][9];

  const int tid = threadIdx.x;
  if (tid < 108) {
    float s, c;
    __sincosf(0.5f * w[tid], &s, &c);
    csn[0][tid] = c;
    csn[1][tid] = s;
  }
  __syncthreads();

  const int wave = tid >> 6;
  if (wave < 2) {  // waves 0,1 redundantly simulate psi0 / psi1
    float ev[9];
    simulate(csn, wave, ev);
    if ((tid & 63) == 0)
#pragma unroll
      for (int ob = 0; ob < 9; ob++) eS[wave][ob] = ev[ob];
  }
  __syncthreads();

  const int b = blockIdx.x * blockDim.x + tid;
  if (b >= B) return;

  const float g = __cosf(cov[2 * b] + w[0]) * __cosf(cov[2 * b + 1] + w[1]) *
                  __cosf(dose[b] + w[2]);
  const float podd = 0.5f * (1.f - g);

#pragma unroll
  for (int q = 0; q < 9; q++) {
    const float e = eS[0][q] + (eS[1][q] - eS[0][q]) * podd;
    const float norm = 0.5f * (e + 1.f);
    if (q < 5) {
      out[b * 5 + q] = pkb[2 * q] + norm * (pkb[2 * q + 1] - pkb[2 * q]);
    } else {
      const int j = q - 5;
      out[B * 5 + b * 4 + j] =
          pdb[2 * j] + norm * (pdb[2 * j + 1] - pdb[2 * j]);
    }
  }
}

// ===========================================================================
extern "C" void kernel_launch(void* const* d_in, const int* in_sizes, int n_in,
                              void* d_out, int out_size, void* d_ws,
                              size_t ws_size, hipStream_t stream) {
  // inputs: 0 subject_ids (unused), 1 covariates (B,2) f32, 2 dose (B,) f32,
  //         3 weights (108,) f32, 4 pk_bounds (5,2) f32, 5 pd_bounds (4,2) f32
  const float* cov = (const float*)d_in[1];
  const float* dose = (const float*)d_in[2];
  const float* wts = (const float*)d_in[3];
  const float* pkb = (const float*)d_in[4];
  const float* pdb = (const float*)d_in[5];
  float* out = (float*)d_out;
  const int B = in_sizes[2];

  hipLaunchKernelGGL(qnpe_fused, dim3((B + 255) / 256), dim3(256), 0, stream,
                     cov, dose, wts, pkb, pdb, out, B);
}

// Round 5
// 71.339 us; speedup vs baseline: 2.2852x; 1.0341x over previous
//
#include <hip/hip_runtime.h>

// ===========================================================================
// Exact algebraic reduction (verified rounds 2-4, absmax <= 1 bf16 ulp):
//   ev_q(b) = e0_q + (e1_q - e0_q) * Podd(b)
//   Podd(b) = 0.5*(1 - cos(t0+W00)cos(t1+W01)cos(t2+W02))
//   e0/e1 from two 512-dim sims (psi0 = V|chi>, psi1 = V X^x9 |chi>).
// Sims live in one wave's registers: 8 complex amps/lane; amp bits 0..2 =
// register (qubits 9,10,11), bits 3..8 = lane (qubits 3..8).
//
// Round-5 changes (chain shortening; round-4 kernel ~18us = shfl/VALU chain):
//  1. layer 0/1 + X^9 folded into a product-state init (LDS factor table).
//  2. layers 6/7 and 8 fused into one SU(2) layer (coeffs precomputed).
//  3. measurement via one Walsh-Hadamard butterfly (6 shfl for 6 lane-obs).
//  4. batch cov/dose loads hoisted above the sim (latency overlap).
// ===========================================================================

typedef float2 cplx;
__device__ inline cplx cmul(cplx a, cplx b) {
  return make_float2(a.x * b.x - a.y * b.y, a.x * b.y + a.y * b.x);
}
__device__ inline cplx cshfl_xor(cplx v, int m) {
  return make_float2(__shfl_xor(v.x, m, 64), __shfl_xor(v.y, m, 64));
}

// --- RY(thy) then RZ(thz) on bit-position BP (0..8) ------------------------
template <int BP>
__device__ inline void rot_gate(cplx (&a)[8], float c, float s, float cz,
                                float sz) {
  if constexpr (BP < 3) {  // register qubit
    constexpr int m = 1 << BP;
#pragma unroll
    for (int r = 0; r < 8; r++)
      if (!(r & m)) {
        const int r1 = r | m;
        const cplx a0 = a[r], a1 = a[r1];
        const float n0x = c * a0.x - s * a1.x, n0y = c * a0.y - s * a1.y;
        const float n1x = s * a0.x + c * a1.x, n1y = s * a0.y + c * a1.y;
        a[r] = make_float2(cz * n0x + sz * n0y, cz * n0y - sz * n0x);
        a[r1] = make_float2(cz * n1x - sz * n1y, cz * n1y + sz * n1x);
      }
  } else {  // lane qubit
    constexpr int lm = 1 << (BP - 3);
    const int bit = (threadIdx.x >> (BP - 3)) & 1;
    const float sy = bit ? s : -s;
    const float so = bit ? -sz : sz;
#pragma unroll
    for (int r = 0; r < 8; r++) {
      const cplx p = cshfl_xor(a[r], lm);
      const float nx = c * a[r].x + sy * p.x, ny = c * a[r].y + sy * p.y;
      a[r] = make_float2(cz * nx + so * ny, cz * ny - so * nx);
    }
  }
}

// --- general SU(2) gate (fused RY*RZ*RY layer) -----------------------------
template <int BP>
__device__ inline void su2_gate(cplx (&a)[8], cplx u00, cplx u01, cplx u10,
                                cplx u11) {
  if constexpr (BP < 3) {
    constexpr int m = 1 << BP;
#pragma unroll
    for (int r = 0; r < 8; r++)
      if (!(r & m)) {
        const int r1 = r | m;
        const cplx a0 = a[r], a1 = a[r1];
        const cplx t0 = cmul(u00, a0), t1 = cmul(u01, a1);
        const cplx t2 = cmul(u10, a0), t3 = cmul(u11, a1);
        a[r] = make_float2(t0.x + t1.x, t0.y + t1.y);
        a[r1] = make_float2(t2.x + t3.x, t2.y + t3.y);
      }
  } else {
    constexpr int lm = 1 << (BP - 3);
    const int bit = (threadIdx.x >> (BP - 3)) & 1;
    const cplx uA = bit ? u11 : u00;
    const cplx uB = bit ? u10 : u01;
#pragma unroll
    for (int r = 0; r < 8; r++) {
      const cplx p = cshfl_xor(a[r], lm);
      const cplx t0 = cmul(uA, a[r]), t1 = cmul(uB, p);
      a[r] = make_float2(t0.x + t1.x, t0.y + t1.y);
    }
  }
}

// --- CNOTs by operand location ---------------------------------------------
template <int CB, int TB>
__device__ inline void cnot_rr(cplx (&a)[8]) {
#pragma unroll
  for (int r = 0; r < 8; r++)
    if ((r & (1 << CB)) && !(r & (1 << TB))) {
      const int r1 = r | (1 << TB);
      const cplx t = a[r];
      a[r] = a[r1];
      a[r1] = t;
    }
}
template <int CB, int TL>
__device__ inline void cnot_rl(cplx (&a)[8]) {
#pragma unroll
  for (int r = 0; r < 8; r++)
    if (r & (1 << CB)) a[r] = cshfl_xor(a[r], 1 << TL);
}
template <int CL, int TB>
__device__ inline void cnot_lr(cplx (&a)[8]) {
  const bool c = (threadIdx.x >> CL) & 1;
#pragma unroll
  for (int r = 0; r < 8; r++)
    if (!(r & (1 << TB))) {
      const int r1 = r | (1 << TB);
      const cplx t0 = a[r];
      a[r] = c ? a[r1] : a[r];
      a[r1] = c ? t0 : a[r1];
    }
}
template <int CL, int TL>
__device__ inline void cnot_ll(cplx (&a)[8]) {
  const bool c = (threadIdx.x >> CL) & 1;
#pragma unroll
  for (int r = 0; r < 8; r++) {
    const cplx p = cshfl_xor(a[r], 1 << TL);
    a[r] = c ? p : a[r];
  }
}

// ===========================================================================
__global__ __launch_bounds__(256) void qnpe_fused(
    const float* __restrict__ cov, const float* __restrict__ dose,
    const float* __restrict__ w, const float* __restrict__ pkb,
    const float* __restrict__ pdb, float* __restrict__ out, int B) {
  __shared__ float csn[2][108];  // cos/sin of 0.5*w[i]
  __shared__ cplx F[9][2];       // per-qubit init factors (layer 0/1 on |0>)
  __shared__ cplx G[2][8];       // reg-qubit init products, per flip-state s
  __shared__ cplx Ug[9][4];      // fused layer-678 SU(2): u00,u01,u10,u11
  __shared__ float eS[2][9];

  const int tid = threadIdx.x;
  const int b = blockIdx.x * 256 + tid;

  // hoist batch loads above the sim chain (latency overlap)
  float x0 = 0.f, x1 = 0.f, x2 = 0.f;
  if (b < B) {
    x0 = cov[2 * b];
    x1 = cov[2 * b + 1];
    x2 = dose[b];
  }
  const float w0 = w[0], w1 = w[1], w2 = w[2];

  if (tid < 108) {
    float s, c;
    __sincosf(0.5f * w[tid], &s, &c);
    csn[0][tid] = c;
    csn[1][tid] = s;
  }
  __syncthreads();

  if (tid < 9) {  // F_q: RZ(W1)*RY(W0)|0> factors, qubit 3+tid
    const float c0 = csn[0][3 + tid], s0 = csn[1][3 + tid];
    const float cz = csn[0][12 + 3 + tid], sz = csn[1][12 + 3 + tid];
    F[tid][0] = make_float2(c0 * cz, -c0 * sz);
    F[tid][1] = make_float2(s0 * cz, s0 * sz);
  } else if (tid >= 16 && tid < 25) {  // fused U = RY(w8)*RZ(w7)*RY(w6)
    const int q = tid - 16;
    const float c6 = csn[0][6 * 12 + 3 + q], s6 = csn[1][6 * 12 + 3 + q];
    const float c7 = csn[0][7 * 12 + 3 + q], s7 = csn[1][7 * 12 + 3 + q];
    const float c8 = csn[0][8 * 12 + 3 + q], s8 = csn[1][8 * 12 + 3 + q];
    const cplx em = make_float2(c7, -s7), ep = make_float2(c7, s7);
    const cplx M00 = make_float2(c6 * em.x, c6 * em.y);
    const cplx M01 = make_float2(-s6 * em.x, -s6 * em.y);
    const cplx M10 = make_float2(s6 * ep.x, s6 * ep.y);
    const cplx M11 = make_float2(c6 * ep.x, c6 * ep.y);
    Ug[q][0] = make_float2(c8 * M00.x - s8 * M10.x, c8 * M00.y - s8 * M10.y);
    Ug[q][1] = make_float2(c8 * M01.x - s8 * M11.x, c8 * M01.y - s8 * M11.y);
    Ug[q][2] = make_float2(s8 * M00.x + c8 * M10.x, s8 * M00.y + c8 * M10.y);
    Ug[q][3] = make_float2(s8 * M01.x + c8 * M11.x, s8 * M01.y + c8 * M11.y);
  }
  __syncthreads();

  if (tid < 16) {  // reg-qubit init products (qubits 9,10,11 = F[6..8])
    const int s = tid >> 3, r = tid & 7;
    cplx g = cmul(F[6][((r >> 2) & 1) ^ s], F[7][((r >> 1) & 1) ^ s]);
    G[s][r] = cmul(g, F[8][(r & 1) ^ s]);
  }
  __syncthreads();

  const int wave = tid >> 6;
  if (wave < 2) {  // wave s simulates psi_s
    const int lane = tid & 63;
    const int s = wave;
    cplx a[8];
    // product-state init: P over lane qubits (3..8 -> lane bits 5..0)
    cplx P = F[0][((lane >> 5) & 1) ^ s];
    P = cmul(P, F[1][((lane >> 4) & 1) ^ s]);
    P = cmul(P, F[2][((lane >> 3) & 1) ^ s]);
    P = cmul(P, F[3][((lane >> 2) & 1) ^ s]);
    P = cmul(P, F[4][((lane >> 1) & 1) ^ s]);
    P = cmul(P, F[5][(lane & 1) ^ s]);
#pragma unroll
    for (int r = 0; r < 8; r++) a[r] = cmul(P, G[s][r]);

#define ROTQ(Q, BP, LY, LZ)                                               \
  rot_gate<BP>(a, csn[0][(LY)*12 + (Q)], csn[1][(LY)*12 + (Q)],           \
               csn[0][(LZ)*12 + (Q)], csn[1][(LZ)*12 + (Q)]);
    // rot layer W2/W3
    ROTQ(3, 8, 2, 3) ROTQ(4, 7, 2, 3) ROTQ(5, 6, 2, 3)
    ROTQ(6, 5, 2, 3) ROTQ(7, 4, 2, 3) ROTQ(8, 3, 2, 3)
    ROTQ(9, 2, 2, 3) ROTQ(10, 1, 2, 3) ROTQ(11, 0, 2, 3)
    // pk ring (3,4)(4,5)(5,6)(6,7)(7,3)
    cnot_ll<5, 4>(a);
    cnot_ll<4, 3>(a);
    cnot_ll<3, 2>(a);
    cnot_ll<2, 1>(a);
    cnot_ll<1, 5>(a);
    // pd ring (8,9)(9,10)(10,11)(11,8)
    cnot_lr<0, 2>(a);
    cnot_rr<2, 1>(a);
    cnot_rr<1, 0>(a);
    cnot_rl<0, 0>(a);
    // rot layer W4/W5
    ROTQ(3, 8, 4, 5) ROTQ(4, 7, 4, 5) ROTQ(5, 6, 4, 5)
    ROTQ(6, 5, 4, 5) ROTQ(7, 4, 4, 5) ROTQ(8, 3, 4, 5)
    ROTQ(9, 2, 4, 5) ROTQ(10, 1, 4, 5) ROTQ(11, 0, 4, 5)
#undef ROTQ
    // cross (3,8)(4,9)(5,10)(6,11)(7,8)
    cnot_ll<5, 0>(a);
    cnot_lr<4, 2>(a);
    cnot_lr<3, 1>(a);
    cnot_lr<2, 0>(a);
    cnot_ll<1, 0>(a);
    // fused layer W6/W7/W8
    su2_gate<8>(a, Ug[0][0], Ug[0][1], Ug[0][2], Ug[0][3]);
    su2_gate<7>(a, Ug[1][0], Ug[1][1], Ug[1][2], Ug[1][3]);
    su2_gate<6>(a, Ug[2][0], Ug[2][1], Ug[2][2], Ug[2][3]);
    su2_gate<5>(a, Ug[3][0], Ug[3][1], Ug[3][2], Ug[3][3]);
    su2_gate<4>(a, Ug[4][0], Ug[4][1], Ug[4][2], Ug[4][3]);
    su2_gate<3>(a, Ug[5][0], Ug[5][1], Ug[5][2], Ug[5][3]);
    su2_gate<2>(a, Ug[6][0], Ug[6][1], Ug[6][2], Ug[6][3]);
    su2_gate<1>(a, Ug[7][0], Ug[7][1], Ug[7][2], Ug[7][3]);
    su2_gate<0>(a, Ug[8][0], Ug[8][1], Ug[8][2], Ug[8][3]);

    // measurement
    float p[8], tot = 0.f;
#pragma unroll
    for (int r = 0; r < 8; r++) {
      p[r] = a[r].x * a[r].x + a[r].y * a[r].y;
      tot += p[r];
    }
    // Walsh-Hadamard butterfly: lane L ends with sum_l (-1)^{popc(l&L)} tot_l
    float v = tot;
#pragma unroll
    for (int k = 0; k < 6; k++) {
      const float pr = __shfl_xor(v, 1 << k, 64);
      v = ((lane >> k) & 1) ? (pr - v) : (v + pr);
    }
    // obs ob (0..5) measures lane bit 5-ob -> WHT index 32>>ob
    if (lane == 32) eS[s][0] = v;
    if (lane == 16) eS[s][1] = v;
    if (lane == 8) eS[s][2] = v;
    if (lane == 4) eS[s][3] = v;
    if (lane == 2) eS[s][4] = v;
    if (lane == 1) eS[s][5] = v;
    // reg-bit observables (ob 6,7,8 -> reg bit 2,1,0)
    float v6 = 0.f, v7 = 0.f, v8 = 0.f;
#pragma unroll
    for (int r = 0; r < 8; r++) {
      v6 += ((r >> 2) & 1) ? -p[r] : p[r];
      v7 += ((r >> 1) & 1) ? -p[r] : p[r];
      v8 += (r & 1) ? -p[r] : p[r];
    }
#pragma unroll
    for (int off = 1; off < 64; off <<= 1) {
      v6 += __shfl_xor(v6, off, 64);
      v7 += __shfl_xor(v7, off, 64);
      v8 += __shfl_xor(v8, off, 64);
    }
    if (lane == 0) {
      eS[s][6] = v6;
      eS[s][7] = v7;
      eS[s][8] = v8;
    }
  }
  __syncthreads();

  if (b >= B) return;
  const float g = __cosf(x0 + w0) * __cosf(x1 + w1) * __cosf(x2 + w2);
  const float podd = 0.5f * (1.f - g);

#pragma unroll
  for (int q = 0; q < 9; q++) {
    const float e = eS[0][q] + (eS[1][q] - eS[0][q]) * podd;
    const float norm = 0.5f * (e + 1.f);
    if (q < 5) {
      out[b * 5 + q] = pkb[2 * q] + norm * (pkb[2 * q + 1] - pkb[2 * q]);
    } else {
      const int j = q - 5;
      out[B * 5 + b * 4 + j] =
          pdb[2 * j] + norm * (pdb[2 * j + 1] - pdb[2 * j]);
    }
  }
}

// ===========================================================================
extern "C" void kernel_launch(void* const* d_in, const int* in_sizes, int n_in,
                              void* d_out, int out_size, void* d_ws,
                              size_t ws_size, hipStream_t stream) {
  // inputs: 0 subject_ids (unused), 1 covariates (B,2) f32, 2 dose (B,) f32,
  //         3 weights (108,) f32, 4 pk_bounds (5,2) f32, 5 pd_bounds (4,2) f32
  const float* cov = (const float*)d_in[1];
  const float* dose = (const float*)d_in[2];
  const float* wts = (const float*)d_in[3];
  const float* pkb = (const float*)d_in[4];
  const float* pdb = (const float*)d_in[5];
  float* out = (float*)d_out;
  const int B = in_sizes[2];

  hipLaunchKernelGGL(qnpe_fused, dim3((B + 255) / 256), dim3(256), 0, stream,
                     cov, dose, wts, pkb, pdb, out, B);
}